// Round 7
// baseline (736.982 us; speedup 1.0000x reference)
//
#include <hip/hip_runtime.h>

// (V, D, H, L, E) = (50000, 128, 128, 4, 160000)
#define V_NODES 50000
#define NEDGE   160000
#define NSEG    (8 * V_NODES)          // 400000 (g,node) segments
#define NPOS    192                    // owned sorted positions per block
#define NTOT    256                    // computed positions (owned + 64 halo)

typedef __bf16 bf16;
typedef __attribute__((ext_vector_type(8))) __bf16 bf16x8;
typedef __attribute__((ext_vector_type(4))) __bf16 bf16x4;
typedef __attribute__((ext_vector_type(4))) float  f32x4;

__device__ __forceinline__ int clampV(int n) {
  unsigned u = (unsigned)n;
  return (int)(u < (unsigned)V_NODES ? u : (unsigned)(V_NODES - 1));
}

// ---------------- prep kernels: fp32 -> bf16 (weights transposed) ----------

__global__ __launch_bounds__(256) void prep_emb_k(const float* __restrict__ in,
                                                  bf16* __restrict__ out) {
  int i = blockIdx.x * 256 + threadIdx.x;
  float4 v = ((const float4*)in)[i];
  bf16x4 o = {(bf16)v.x, (bf16)v.y, (bf16)v.z, (bf16)v.w};
  *(bf16x4*)(out + (size_t)i * 4) = o;
}

__global__ __launch_bounds__(256) void prep_w1_k(const float* __restrict__ in,
                                                 bf16* __restrict__ out) {
  int idx = blockIdx.x * 256 + threadIdx.x;         // 262144
  int n = idx & 127, k = (idx >> 7) & 255, g = idx >> 15;
  out[(((g << 7) + n) << 8) + k] = (bf16)in[idx];
}

__global__ __launch_bounds__(256) void prep_w2_k(const float* __restrict__ in,
                                                 bf16* __restrict__ out) {
  int idx = blockIdx.x * 256 + threadIdx.x;         // 131072
  int n = idx & 127, k = (idx >> 7) & 127, g = idx >> 14;
  out[(((g << 7) + n) << 7) + k] = (bf16)in[idx];
}

__global__ __launch_bounds__(256) void relu_k(float* __restrict__ out) {
  int i = blockIdx.x * 256 + threadIdx.x;
  float4 v = ((float4*)out)[i];
  v.x = fmaxf(v.x, 0.f); v.y = fmaxf(v.y, 0.f);
  v.z = fmaxf(v.z, 0.f); v.w = fmaxf(v.w, 0.f);
  ((float4*)out)[i] = v;
}

// ---------------- CSR build (sort edge slots by (g, target node)) ----------

__global__ __launch_bounds__(256) void hist_k(
    const int* __restrict__ a0, const int* __restrict__ a1,
    const int* __restrict__ a2, const int* __restrict__ a3,
    int* __restrict__ counts) {
  int e = blockIdx.x * 256 + threadIdx.x;    // 0..159999
  int g = blockIdx.y;                        // 0..7
  int l = g >> 1, ep = g & 1;
  const int* adj = (l == 0) ? a0 : (l == 1) ? a1 : (l == 2) ? a2 : a3;
  int tgt = clampV(adj[2 * e + ep]);
  atomicAdd(&counts[g * V_NODES + tgt], 1);
}

__global__ __launch_bounds__(256) void scan_a_k(const int* __restrict__ counts,
                                                int* __restrict__ offs,
                                                int* __restrict__ bsums) {
  __shared__ int sh[256];
  int t = threadIdx.x, base = blockIdx.x * 512;
  int e0 = base + 2 * t, e1 = e0 + 1;
  int a = (e0 < NSEG) ? counts[e0] : 0;
  int b = (e1 < NSEG) ? counts[e1] : 0;
  int s = a + b;
  sh[t] = s;
  __syncthreads();
  #pragma unroll
  for (int d = 1; d < 256; d <<= 1) {
    int v = (t >= d) ? sh[t - d] : 0;
    __syncthreads();
    sh[t] += v;
    __syncthreads();
  }
  int excl = sh[t] - s;
  if (e0 < NSEG) offs[e0] = excl;
  if (e1 < NSEG) offs[e1] = excl + a;
  if (t == 255) bsums[blockIdx.x] = sh[255];
}

#define NBLK_SCAN 782   // ceil(400000/512)

__global__ __launch_bounds__(256) void scan_b_k(int* __restrict__ bsums,
                                                int* __restrict__ offs) {
  __shared__ int sh[NBLK_SCAN];
  int t = threadIdx.x;
  for (int i = t; i < NBLK_SCAN; i += 256) sh[i] = bsums[i];
  __syncthreads();
  if (t == 0) {
    int run = 0;
    for (int i = 0; i < NBLK_SCAN; ++i) { int v = sh[i]; sh[i] = run; run += v; }
    offs[NSEG] = run;
  }
  __syncthreads();
  for (int i = t; i < NBLK_SCAN; i += 256) bsums[i] = sh[i];
}

__global__ __launch_bounds__(256) void scan_c_k(int* __restrict__ offs,
                                                const int* __restrict__ bsums) {
  int i = blockIdx.x * 256 + threadIdx.x;
  if (i < NSEG) offs[i] += bsums[i >> 9];
}

__global__ __launch_bounds__(256) void scatter_ids_k(
    const int* __restrict__ a0, const int* __restrict__ a1,
    const int* __restrict__ a2, const int* __restrict__ a3,
    const int* __restrict__ offs, int* __restrict__ cursor,
    int* __restrict__ ids) {
  int e = blockIdx.x * 256 + threadIdx.x;
  int g = blockIdx.y;
  int l = g >> 1, ep = g & 1;
  const int* adj = (l == 0) ? a0 : (l == 1) ? a1 : (l == 2) ? a2 : a3;
  int seg = g * V_NODES + clampV(adj[2 * e + ep]);
  int pos = offs[seg] + atomicAdd(&cursor[seg], 1);
  ids[pos] = e;
}

// ---------------- fused GEMM1 + segmented aggregation ----------------------
// Block: 192 owned sorted positions (+64 halo) of group g = gbase+blockIdx.y.
// Phase 1: register-resident W1^T MFMA -> relu(h) into swizzled LDS tile.
// Phase 2: detect segment starts (node change) in owned range; each wave sums
// full segments (may extend into halo) and plain-stores packed bf16 to Hagg.
// LDS h swizzle: dim-chunk (4 bf16 = 8 B) c stored at c ^ (pos & 15):
// reduction reads (u32/lane over 64 lanes) become conflict-free bijections.

__global__ __launch_bounds__(256, 2) void fused_k(
    const bf16* __restrict__ embB,
    const int* __restrict__ a0, const int* __restrict__ a1,
    const int* __restrict__ a2, const int* __restrict__ a3,
    const bf16* __restrict__ w1t,
    const int* __restrict__ ids,
    bf16* __restrict__ Hagg,
    int gbase) {

  __shared__ __attribute__((aligned(16))) bf16 h_lds[NTOT * 128]; // 65536 B
  __shared__ int2 pairs_lds[NTOT];                                // 2048 B
  __shared__ int  nds_lds[NTOT];                                  // 1024 B
  __shared__ int  starts_lds[NPOS];                               // 768 B
  __shared__ int  cnt_lds;
  __shared__ int  prev_lds;

  const int tid = threadIdx.x;
  const int g  = gbase + blockIdx.y;
  const int l = g >> 1, ep = g & 1;
  const int* __restrict__ adj = (l == 0) ? a0 : (l == 1) ? a1 : (l == 2) ? a2 : a3;
  const int bl = blockIdx.x;
  const int p0 = g * NEDGE + bl * NPOS;
  const int gend = (g + 1) * NEDGE;
  const int rem = gend - p0;                 // >= 64 by grid construction
  const int ntv = rem < NTOT ? rem : NTOT;   // valid computed positions
  const int npo = rem < NPOS ? rem : NPOS;   // owned positions

  if (tid == 0) {
    cnt_lds = 0;
    prev_lds = (bl > 0) ? clampV(adj[2 * ids[p0 - 1] + ep]) : -2;
  }
  {
    int2 pr = {0, 0};
    int nd = -1;
    if (tid < ntv) {
      int e = ids[p0 + tid];
      pr = ((const int2*)adj)[e];
      pr.x = clampV(pr.x); pr.y = clampV(pr.y);
      nd = ep ? pr.y : pr.x;
    }
    pairs_lds[tid] = pr;
    nds_lds[tid] = nd;
  }

  const int w = tid >> 6, lane = tid & 63;
  const int dh = w & 1, sub = w >> 1;        // dims-half, position sub-tile
  const int l15 = lane & 15, q = lane >> 4;

  // W1^T A-fragments in registers: A[m=16mb+l15][k=kb*32+q*8+j]
  bf16x8 wA[4][8];
  const bf16* w1row = w1t + ((size_t)(g * 128 + dh * 64)) * 256;
  #pragma unroll
  for (int mb = 0; mb < 4; ++mb)
    #pragma unroll
    for (int kb = 0; kb < 8; ++kb)
      wA[mb][kb] = *(const bf16x8*)(w1row + (mb * 16 + l15) * 256 + kb * 32 + q * 8);

  __syncthreads();   // staging visible

  #pragma unroll
  for (int t = 0; t < 8; ++t) {
    const int j = t * 32 + sub * 16 + l15;   // local position (LDS row)
    int2 pr = pairs_lds[j];
    bf16x8 b[8];
    #pragma unroll
    for (int kb = 0; kb < 8; ++kb) {
      const int node = (kb < 4) ? pr.x : pr.y;
      const int klo = (kb * 32 + q * 8) & 127;
      b[kb] = *(const bf16x8*)(embB + (size_t)node * 128 + klo);
    }
    f32x4 acc[4] = {};
    #pragma unroll
    for (int kb = 0; kb < 8; ++kb)
      #pragma unroll
      for (int mb = 0; mb < 4; ++mb)
        acc[mb] = __builtin_amdgcn_mfma_f32_16x16x32_bf16(wA[mb][kb], b[kb], acc[mb], 0, 0, 0);
    // relu + swizzled store: dims 16mb+4q+0..3 (+64dh) -> chunk c ^ (j&15)
    #pragma unroll
    for (int mb = 0; mb < 4; ++mb) {
      const int c = (dh << 4) | (mb << 2) | q;
      bf16x4 o = {(bf16)fmaxf(acc[mb][0], 0.f), (bf16)fmaxf(acc[mb][1], 0.f),
                  (bf16)fmaxf(acc[mb][2], 0.f), (bf16)fmaxf(acc[mb][3], 0.f)};
      *(bf16x4*)(&h_lds[j * 128 + ((c ^ (j & 15)) << 2)]) = o;
    }
  }
  __syncthreads();   // h + nds visible

  // segment starts in owned range
  if (tid < npo) {
    int nd = nds_lds[tid];
    int pv = tid ? nds_lds[tid - 1] : prev_lds;
    if (nd != pv) {
      int ix = atomicAdd(&cnt_lds, 1);
      starts_lds[ix] = tid;
    }
  }
  __syncthreads();

  // wave-parallel segment reduction: lane owns dims {2*lane, 2*lane+1}
  const int ncnt = cnt_lds;
  const int ch = lane >> 1;                  // dim chunk of this lane
  const int hw = (lane & 1) << 1;            // elem offset within chunk
  bf16* __restrict__ HaggG = Hagg + (size_t)blockIdx.y * V_NODES * 128;
  for (int i = w; i < ncnt; i += 4) {
    int j = starts_lds[i];
    const int node = nds_lds[j];
    float sx = 0.f, sy = 0.f;
    do {
      unsigned u = *(const unsigned*)(&h_lds[j * 128 + ((ch ^ (j & 15)) << 2) + hw]);
      sx += (float)__builtin_bit_cast(bf16, (unsigned short)u);
      sy += (float)__builtin_bit_cast(bf16, (unsigned short)(u >> 16));
      ++j;
    } while (j < ntv && nds_lds[j] == node);
    bf16 plo = (bf16)sx, phi = (bf16)sy;
    unsigned pu = (unsigned)__builtin_bit_cast(unsigned short, plo)
                | ((unsigned)__builtin_bit_cast(unsigned short, phi) << 16);
    *(unsigned*)(HaggG + (size_t)node * 128 + lane * 2) = pu;
  }
}

// ---------------- gemm2: out (+)= sum_{gg} Hagg_gg @ W2_{gbase+gg} ---------

template <bool FINAL>
__global__ __launch_bounds__(256) void gemm2_k(const bf16* __restrict__ Hagg,
                                               const bf16* __restrict__ w2t,
                                               float* __restrict__ out,
                                               int gbase) {
  const int tid = threadIdx.x, wv = tid >> 6, lane = tid & 63;
  const int l15 = lane & 15, q = lane >> 4;
  const int v0 = blockIdx.x * 64;
  const int vr = v0 + wv * 16 + l15;
  const int vc = vr < V_NODES ? vr : V_NODES - 1;

  f32x4 acc[8] = {};
  for (int gg = 0; gg < 4; ++gg) {
    const bf16* Ha = Hagg + ((size_t)gg * V_NODES + vc) * 128;
    const bf16* Wb = w2t + (size_t)(gbase + gg) * 128 * 128;
    #pragma unroll
    for (int kb = 0; kb < 4; ++kb) {
      bf16x8 a = *(const bf16x8*)(Ha + kb * 32 + q * 8);
      #pragma unroll
      for (int nb = 0; nb < 8; ++nb) {
        bf16x8 b = *(const bf16x8*)(Wb + (nb * 16 + l15) * 128 + kb * 32 + q * 8);
        acc[nb] = __builtin_amdgcn_mfma_f32_16x16x32_bf16(a, b, acc[nb], 0, 0, 0);
      }
    }
  }

  const int row = v0 + wv * 16 + q * 4;
  #pragma unroll
  for (int r = 0; r < 4; ++r) {
    if (row + r < V_NODES) {
      #pragma unroll
      for (int nb = 0; nb < 8; ++nb) {
        size_t o = (size_t)(row + r) * 128 + nb * 16 + l15;
        float v = acc[nb][r];
        if (FINAL) out[o] = fmaxf(out[o] + v, 0.f);
        else       out[o] = v;
      }
    }
  }
}

// ---------------- fallback edge kernel (round-4, proven) -------------------

__global__ __launch_bounds__(256) void edge_k(
    const bf16* __restrict__ embB,
    const int* __restrict__ a0, const int* __restrict__ a1,
    const int* __restrict__ a2, const int* __restrict__ a3,
    const bf16* __restrict__ w1t, const bf16* __restrict__ w2t,
    float* __restrict__ out) {

  __shared__ __attribute__((aligned(16))) bf16 w1_lds[128 * 256];
  __shared__ __attribute__((aligned(16))) bf16 h_lds[64 * 128];

  const int tid = threadIdx.x;
  const int g  = blockIdx.x >> 6;
  const int bs = blockIdx.x & 63;
  const int l = g >> 1, ep = g & 1;
  const int* __restrict__ adj = (l == 0) ? a0 : (l == 1) ? a1 : (l == 2) ? a2 : a3;

  {
    const uint4* w1g = (const uint4*)(w1t + (size_t)g * 128 * 256);
    #pragma unroll
    for (int i = 0; i < 16; ++i) {
      int j = i * 256 + tid;
      int n = j >> 5, c = j & 31;
      *(uint4*)(&w1_lds[n * 256 + ((c ^ (n & 7)) << 3)]) = w1g[j];
    }
  }
  __syncthreads();

  const int w    = tid >> 6;
  const int lane = tid & 63;
  const int wr = w >> 1, wc = w & 1;
  const int l15 = lane & 15, q = lane >> 4;
  const bf16* __restrict__ w2g = w2t + (size_t)g * 128 * 128;

  for (int t = bs; t < 2500; t += 64) {
    const int ebase = t * 64;
    int2 pr0 = ((const int2*)adj)[ebase + 32 * wr + l15];
    int2 pr1 = ((const int2*)adj)[ebase + 32 * wr + 16 + l15];
    pr0.x = clampV(pr0.x); pr0.y = clampV(pr0.y);
    pr1.x = clampV(pr1.x); pr1.y = clampV(pr1.y);

    f32x4 acc[2][4] = {};
    #pragma unroll
    for (int kb = 0; kb < 8; ++kb) {
      const int k = kb * 32 + q * 8;
      const int klo = k & 127;
      const int n0 = (kb < 4) ? pr0.x : pr0.y;
      const int n1 = (kb < 4) ? pr1.x : pr1.y;
      bf16x8 a[2], b[4];
      a[0] = *(const bf16x8*)(embB + (size_t)n0 * 128 + klo);
      a[1] = *(const bf16x8*)(embB + (size_t)n1 * 128 + klo);
      const int csw = ((kb << 2) + q);
      #pragma unroll
      for (int nt = 0; nt < 4; ++nt) {
        int n = 64 * wc + 16 * nt + l15;
        b[nt] = *(const bf16x8*)(&w1_lds[n * 256 + ((csw ^ (l15 & 7)) << 3)]);
      }
      #pragma unroll
      for (int mt = 0; mt < 2; ++mt)
        #pragma unroll
        for (int nt = 0; nt < 4; ++nt)
          acc[mt][nt] = __builtin_amdgcn_mfma_f32_16x16x32_bf16(a[mt], b[nt], acc[mt][nt], 0, 0, 0);
    }

    __syncthreads();
    #pragma unroll
    for (int mt = 0; mt < 2; ++mt)
      #pragma unroll
      for (int nt = 0; nt < 4; ++nt)
        #pragma unroll
        for (int r = 0; r < 4; ++r) {
          float v = acc[mt][nt][r];
          v = v > 0.f ? v : 0.f;
          int row = 32 * wr + 16 * mt + 4 * q + r;
          int col = 64 * wc + 16 * nt + l15;
          int c = col >> 3;
          h_lds[row * 128 + (((c ^ (row & 7)) << 3) | (col & 7))] = (bf16)v;
        }
    __syncthreads();

    f32x4 acc2[2][4] = {};
    #pragma unroll
    for (int kb = 0; kb < 4; ++kb) {
      const int k = kb * 32 + q * 8;
      const int csw = (kb << 2) + q;
      bf16x8 a[2], b[4];
      #pragma unroll
      for (int mt = 0; mt < 2; ++mt) {
        int row = 32 * wr + 16 * mt + l15;
        a[mt] = *(const bf16x8*)(&h_lds[row * 128 + ((csw ^ (row & 7)) << 3)]);
      }
      #pragma unroll
      for (int nt = 0; nt < 4; ++nt) {
        int n = 64 * wc + 16 * nt + l15;
        b[nt] = *(const bf16x8*)(w2g + n * 128 + k);
      }
      #pragma unroll
      for (int mt = 0; mt < 2; ++mt)
        #pragma unroll
        for (int nt = 0; nt < 4; ++nt)
          acc2[mt][nt] = __builtin_amdgcn_mfma_f32_16x16x32_bf16(a[mt], b[nt], acc2[mt][nt], 0, 0, 0);
    }

    #pragma unroll
    for (int mt = 0; mt < 2; ++mt)
      #pragma unroll
      for (int r = 0; r < 4; ++r) {
        int row = 32 * wr + 16 * mt + 4 * q + r;
        int2 pr = ((const int2*)adj)[ebase + row];
        int node = clampV(ep ? pr.y : pr.x);
        float* basep = out + (size_t)node * 128 + 64 * wc + l15;
        #pragma unroll
        for (int nt = 0; nt < 4; ++nt)
          unsafeAtomicAdd(basep + 16 * nt, acc2[mt][nt][r]);
      }
  }
}

// ---------------- host launch ----------------------------------------------

extern "C" void kernel_launch(void* const* d_in, const int* in_sizes, int n_in,
                              void* d_out, int out_size, void* d_ws, size_t ws_size,
                              hipStream_t stream) {
  const float* emb = (const float*)d_in[0];
  const int* a0 = (const int*)d_in[1];
  const int* a1 = (const int*)d_in[2];
  const int* a2 = (const int*)d_in[3];
  const int* a3 = (const int*)d_in[4];
  const float* W1 = (const float*)d_in[5];
  const float* W2 = (const float*)d_in[6];
  float* out = (float*)d_out;

  char* ws = (char*)d_ws;
  bf16* embB = (bf16*)(ws);                    // 12,800,000
  bf16* w1t  = (bf16*)(ws + 12800000);         //    524,288
  bf16* w2t  = (bf16*)(ws + 13324288);         //    262,144
  int*  ids  = (int*) (ws + 13586432);         //  5,120,000 (1.28M sorted slots)
  bf16* Hagg = (bf16*)(ws + 18706432);         // 51,200,000 (4 groups / pass)
  // CSR scratch overlays the Hagg region (dead before Hagg's memset):
  int*  counts = (int*)(ws + 18706432);                // 1,600,000
  int*  cursor = (int*)(ws + 18706432 + 1600000);      // 1,600,000
  int*  offs   = (int*)(ws + 18706432 + 3200000);      // 1,600,004
  int*  bsums  = (int*)(ws + 18706432 + 4800004);      //     3,128
  const size_t need_full = 69906432;           // ~70 MB (< known 116 MB floor)

  prep_emb_k<<<6250, 256, 0, stream>>>(emb, embB);
  prep_w1_k<<<1024, 256, 0, stream>>>(W1, w1t);
  prep_w2_k<<<512, 256, 0, stream>>>(W2, w2t);

  if (ws_size >= need_full) {
    hipMemsetAsync(counts, 0, 3200000, stream);        // counts + cursor
    hist_k<<<dim3(625, 8), 256, 0, stream>>>(a0, a1, a2, a3, counts);
    scan_a_k<<<NBLK_SCAN, 256, 0, stream>>>(counts, offs, bsums);
    scan_b_k<<<1, 256, 0, stream>>>(bsums, offs);
    scan_c_k<<<1563, 256, 0, stream>>>(offs, bsums);
    scatter_ids_k<<<dim3(625, 8), 256, 0, stream>>>(a0, a1, a2, a3, offs, cursor, ids);

    // pass 1: groups 0..3
    hipMemsetAsync(Hagg, 0, 51200000, stream);
    fused_k<<<dim3(834, 4), 256, 0, stream>>>(embB, a0, a1, a2, a3, w1t, ids, Hagg, 0);
    gemm2_k<false><<<782, 256, 0, stream>>>(Hagg, w2t, out, 0);
    // pass 2: groups 4..7
    hipMemsetAsync(Hagg, 0, 51200000, stream);
    fused_k<<<dim3(834, 4), 256, 0, stream>>>(embB, a0, a1, a2, a3, w1t, ids, Hagg, 4);
    gemm2_k<true><<<782, 256, 0, stream>>>(Hagg, w2t, out, 4);
  } else {
    hipMemsetAsync(d_out, 0, (size_t)V_NODES * 128 * sizeof(float), stream);
    edge_k<<<512, 256, 0, stream>>>(embB, a0, a1, a2, a3, w1t, w2t, out);
    relu_k<<<6250, 256, 0, stream>>>(out);
  }
}

// Round 8
// 694.072 us; speedup vs baseline: 1.0618x; 1.0618x over previous
//
#include <hip/hip_runtime.h>

// (V, D, H, L, E) = (50000, 128, 128, 4, 160000)
#define V_NODES 50000
#define NEDGE   160000
#define NSEG    (8 * V_NODES)          // 400000 (g,node) segments
#define NPOS    224                    // owned sorted positions per block
#define NTOT    256                    // computed positions (owned + 32 halo)
#define NBLK_FUSED 715                 // ceil(160000/224)

typedef __bf16 bf16;
typedef __attribute__((ext_vector_type(8))) __bf16 bf16x8;
typedef __attribute__((ext_vector_type(4))) __bf16 bf16x4;
typedef __attribute__((ext_vector_type(4))) float  f32x4;

__device__ __forceinline__ int clampV(int n) {
  unsigned u = (unsigned)n;
  return (int)(u < (unsigned)V_NODES ? u : (unsigned)(V_NODES - 1));
}

// ---------------- prep kernels --------------------------------------------

__global__ __launch_bounds__(256) void prep_emb_k(const float* __restrict__ in,
                                                  bf16* __restrict__ out) {
  int i = blockIdx.x * 256 + threadIdx.x;
  float4 v = ((const float4*)in)[i];
  bf16x4 o = {(bf16)v.x, (bf16)v.y, (bf16)v.z, (bf16)v.w};
  *(bf16x4*)(out + (size_t)i * 4) = o;
}

// W1: (4,2,256,128)->W1T[g][n][k=256]; W2: (4,2,128,128)->W2T[g][n][k=128]
__global__ __launch_bounds__(256) void prep_w_k(const float* __restrict__ W1,
                                                const float* __restrict__ W2,
                                                bf16* __restrict__ w1t,
                                                bf16* __restrict__ w2t) {
  int idx = blockIdx.x * 256 + threadIdx.x;   // 393216 jobs
  if (idx < 262144) {
    int n = idx & 127, k = (idx >> 7) & 255, g = idx >> 15;
    w1t[(((g << 7) + n) << 8) + k] = (bf16)W1[idx];
  } else {
    int j = idx - 262144;
    int n = j & 127, k = (j >> 7) & 127, g = j >> 14;
    w2t[(((g << 7) + n) << 7) + k] = (bf16)W2[j];
  }
}

__global__ __launch_bounds__(256) void relu_k(float* __restrict__ out) {
  int i = blockIdx.x * 256 + threadIdx.x;
  float4 v = ((float4*)out)[i];
  v.x = fmaxf(v.x, 0.f); v.y = fmaxf(v.y, 0.f);
  v.z = fmaxf(v.z, 0.f); v.w = fmaxf(v.w, 0.f);
  ((float4*)out)[i] = v;
}

// ---------------- CSR build (sort edge slots by (g, target node)) ----------

__global__ __launch_bounds__(256) void hist_k(
    const int* __restrict__ a0, const int* __restrict__ a1,
    const int* __restrict__ a2, const int* __restrict__ a3,
    int* __restrict__ counts) {
  int e = blockIdx.x * 256 + threadIdx.x;
  int g = blockIdx.y;
  int l = g >> 1, ep = g & 1;
  const int* adj = (l == 0) ? a0 : (l == 1) ? a1 : (l == 2) ? a2 : a3;
  atomicAdd(&counts[g * V_NODES + clampV(adj[2 * e + ep])], 1);
}

__global__ __launch_bounds__(256) void scan_a_k(const int* __restrict__ counts,
                                                int* __restrict__ offs,
                                                int* __restrict__ bsums) {
  __shared__ int sh[256];
  int t = threadIdx.x, base = blockIdx.x * 512;
  int e0 = base + 2 * t, e1 = e0 + 1;
  int a = (e0 < NSEG) ? counts[e0] : 0;
  int b = (e1 < NSEG) ? counts[e1] : 0;
  int s = a + b;
  sh[t] = s;
  __syncthreads();
  #pragma unroll
  for (int d = 1; d < 256; d <<= 1) {
    int v = (t >= d) ? sh[t - d] : 0;
    __syncthreads();
    sh[t] += v;
    __syncthreads();
  }
  int excl = sh[t] - s;
  if (e0 < NSEG) offs[e0] = excl;
  if (e1 < NSEG) offs[e1] = excl + a;
  if (t == 255) bsums[blockIdx.x] = sh[255];
}

#define NBLK_SCAN 782   // ceil(400000/512)

// parallel block-sum scan (replaces single-thread serial loop)
__global__ __launch_bounds__(256) void scan_b_k(int* __restrict__ bsums,
                                                int* __restrict__ offs) {
  __shared__ int sh[256];
  int t = threadIdx.x;
  int v[4]; int s = 0;
  #pragma unroll
  for (int k = 0; k < 4; ++k) {
    int i = t * 4 + k;
    v[k] = (i < NBLK_SCAN) ? bsums[i] : 0;
    s += v[k];
  }
  sh[t] = s;
  __syncthreads();
  #pragma unroll
  for (int d = 1; d < 256; d <<= 1) {
    int x = (t >= d) ? sh[t - d] : 0;
    __syncthreads();
    sh[t] += x;
    __syncthreads();
  }
  int run = sh[t] - s;
  if (t == 255) offs[NSEG] = sh[255];
  #pragma unroll
  for (int k = 0; k < 4; ++k) {
    int i = t * 4 + k;
    if (i < NBLK_SCAN) bsums[i] = run;
    run += v[k];
  }
}

__global__ __launch_bounds__(256) void scan_c_k(int* __restrict__ offs,
                                                const int* __restrict__ bsums) {
  int i = blockIdx.x * 256 + threadIdx.x;
  if (i < NSEG) offs[i] += bsums[i >> 9];
}

__global__ __launch_bounds__(256) void scatter_ids_k(
    const int* __restrict__ a0, const int* __restrict__ a1,
    const int* __restrict__ a2, const int* __restrict__ a3,
    const int* __restrict__ offs, int* __restrict__ cursor,
    int* __restrict__ ids) {
  int e = blockIdx.x * 256 + threadIdx.x;
  int g = blockIdx.y;
  int l = g >> 1, ep = g & 1;
  const int* adj = (l == 0) ? a0 : (l == 1) ? a1 : (l == 2) ? a2 : a3;
  int seg = g * V_NODES + clampV(adj[2 * e + ep]);
  int pos = offs[seg] + atomicAdd(&cursor[seg], 1);
  ids[pos] = e;
}

// ---------------- fused GEMM1 + segmented aggregation (v2) -----------------
// 512 threads = 8 waves: dq = w&3 (32-dim quarter, wA[2][8]=64 VGPR for
// occupancy), sub = w>>2 (16-position half per t-tile). Block owns 224
// sorted positions (+32 halo). Phase 1: register-resident W1^T MFMA ->
// relu(h) into swizzled LDS. Phase 2: 8-way segmented reduction, plain
// packed-bf16 stores to Hagg (no atomics).

__global__ __launch_bounds__(512, 4) void fused_k(
    const bf16* __restrict__ embB,
    const int* __restrict__ a0, const int* __restrict__ a1,
    const int* __restrict__ a2, const int* __restrict__ a3,
    const bf16* __restrict__ w1t,
    const int* __restrict__ ids,
    bf16* __restrict__ Hagg) {

  __shared__ __attribute__((aligned(16))) bf16 h_lds[NTOT * 128]; // 65536 B
  __shared__ int2 pairs_lds[NTOT];                                // 2048 B
  __shared__ int  nds_lds[NTOT];                                  // 1024 B
  __shared__ int  starts_lds[NPOS];                               // 896 B
  __shared__ int  cnt_lds;
  __shared__ int  prev_lds;

  const int tid = threadIdx.x;
  const int g  = blockIdx.y;
  const int l = g >> 1, ep = g & 1;
  const int* __restrict__ adj = (l == 0) ? a0 : (l == 1) ? a1 : (l == 2) ? a2 : a3;
  const int bl = blockIdx.x;
  const int p0 = g * NEDGE + bl * NPOS;
  const int rem = NEDGE - bl * NPOS;         // >= 64 by grid construction
  const int ntv = rem < NTOT ? rem : NTOT;
  const int npo = rem < NPOS ? rem : NPOS;

  if (tid == 0) {
    cnt_lds = 0;
    prev_lds = (bl > 0) ? clampV(adj[2 * ids[p0 - 1] + ep]) : -2;
  }
  if (tid < NTOT) {
    int2 pr = {0, 0};
    int nd = -1;
    if (tid < ntv) {
      int e = ids[p0 + tid];
      pr = ((const int2*)adj)[e];
      pr.x = clampV(pr.x); pr.y = clampV(pr.y);
      nd = ep ? pr.y : pr.x;
    }
    pairs_lds[tid] = pr;
    nds_lds[tid] = nd;
  }

  const int w = tid >> 6, lane = tid & 63;
  const int dq = w & 3, sub = w >> 2;        // dim-quarter, position-sub
  const int l15 = lane & 15, q = lane >> 4;

  // W1^T A-fragments in registers: dims dq*32 + mb*16 + l15, k = kb*32+q*8
  bf16x8 wA[2][8];
  const bf16* w1row = w1t + ((size_t)(g * 128 + dq * 32)) * 256;
  #pragma unroll
  for (int mb = 0; mb < 2; ++mb)
    #pragma unroll
    for (int kb = 0; kb < 8; ++kb)
      wA[mb][kb] = *(const bf16x8*)(w1row + (mb * 16 + l15) * 256 + kb * 32 + q * 8);

  __syncthreads();   // staging visible

  // segment-start detection (overlaps phase-1 issue)
  if (tid < npo) {
    int nd = nds_lds[tid];
    int pv = tid ? nds_lds[tid - 1] : prev_lds;
    if (nd != pv) starts_lds[atomicAdd(&cnt_lds, 1)] = tid;
  }

  // ---- phase 1: h = relu(raw @ W1), 8 t-tiles x 16 positions per wave ----
  #pragma unroll
  for (int t = 0; t < 8; ++t) {
    const int j = t * 32 + sub * 16 + l15;   // local position (LDS row)
    int2 pr = pairs_lds[j];
    bf16x8 b[8];
    #pragma unroll
    for (int kb = 0; kb < 8; ++kb) {
      const int node = (kb < 4) ? pr.x : pr.y;
      const int klo = (kb * 32 + q * 8) & 127;
      b[kb] = *(const bf16x8*)(embB + (size_t)node * 128 + klo);
    }
    f32x4 acc[2] = {};
    #pragma unroll
    for (int kb = 0; kb < 8; ++kb)
      #pragma unroll
      for (int mb = 0; mb < 2; ++mb)
        acc[mb] = __builtin_amdgcn_mfma_f32_16x16x32_bf16(wA[mb][kb], b[kb], acc[mb], 0, 0, 0);
    // dims dq*32+mb*16+q*4+r of position j; chunk c = dim>>2, swizzled
    #pragma unroll
    for (int mb = 0; mb < 2; ++mb) {
      const int c = (dq << 3) | (mb << 2) | q;
      bf16x4 o = {(bf16)fmaxf(acc[mb][0], 0.f), (bf16)fmaxf(acc[mb][1], 0.f),
                  (bf16)fmaxf(acc[mb][2], 0.f), (bf16)fmaxf(acc[mb][3], 0.f)};
      *(bf16x4*)(&h_lds[j * 128 + ((c ^ (j & 15)) << 2)]) = o;
    }
  }
  __syncthreads();   // h + starts visible

  // ---- phase 2: 8-way wave-parallel segment reduction ----
  const int ncnt = cnt_lds;
  const int ch = lane >> 1;                  // dim chunk of this lane
  const int hw = (lane & 1) << 1;            // elem offset within chunk
  bf16* __restrict__ HaggG = Hagg + (size_t)g * V_NODES * 128;
  for (int i = w; i < ncnt; i += 8) {
    int j = starts_lds[i];
    const int node = nds_lds[j];
    float sx = 0.f, sy = 0.f;
    do {
      unsigned u = *(const unsigned*)(&h_lds[j * 128 + ((ch ^ (j & 15)) << 2) + hw]);
      sx += (float)__builtin_bit_cast(bf16, (unsigned short)u);
      sy += (float)__builtin_bit_cast(bf16, (unsigned short)(u >> 16));
      ++j;
    } while (j < ntv && nds_lds[j] == node);
    bf16 plo = (bf16)sx, phi = (bf16)sy;
    unsigned pu = (unsigned)__builtin_bit_cast(unsigned short, plo)
                | ((unsigned)__builtin_bit_cast(unsigned short, phi) << 16);
    *(unsigned*)(HaggG + (size_t)node * 128 + lane * 2) = pu;
  }
}

// ---------------- final GEMM: out = relu(sum_g Hagg_g @ W2_g) --------------

__global__ __launch_bounds__(256) void gemm2_k(const bf16* __restrict__ Hagg,
                                               const bf16* __restrict__ w2t,
                                               float* __restrict__ out) {
  const int tid = threadIdx.x, wv = tid >> 6, lane = tid & 63;
  const int l15 = lane & 15, q = lane >> 4;
  const int v0 = blockIdx.x * 64;
  const int vr = v0 + wv * 16 + l15;
  const int vc = vr < V_NODES ? vr : V_NODES - 1;

  f32x4 acc[8] = {};
  for (int g = 0; g < 8; ++g) {
    const bf16* Ha = Hagg + ((size_t)g * V_NODES + vc) * 128;
    const bf16* Wb = w2t + (size_t)g * 128 * 128;
    #pragma unroll
    for (int kb = 0; kb < 4; ++kb) {
      bf16x8 a = *(const bf16x8*)(Ha + kb * 32 + q * 8);
      #pragma unroll
      for (int nb = 0; nb < 8; ++nb) {
        bf16x8 b = *(const bf16x8*)(Wb + (nb * 16 + l15) * 128 + kb * 32 + q * 8);
        acc[nb] = __builtin_amdgcn_mfma_f32_16x16x32_bf16(a, b, acc[nb], 0, 0, 0);
      }
    }
  }

  const int row = v0 + wv * 16 + q * 4;
  #pragma unroll
  for (int r = 0; r < 4; ++r) {
    if (row + r < V_NODES) {
      #pragma unroll
      for (int nb = 0; nb < 8; ++nb)
        out[(size_t)(row + r) * 128 + nb * 16 + l15] = fmaxf(acc[nb][r], 0.f);
    }
  }
}

// ---------------- fallback edge kernel (round-4, proven) -------------------

__global__ __launch_bounds__(256) void edge_k(
    const bf16* __restrict__ embB,
    const int* __restrict__ a0, const int* __restrict__ a1,
    const int* __restrict__ a2, const int* __restrict__ a3,
    const bf16* __restrict__ w1t, const bf16* __restrict__ w2t,
    float* __restrict__ out) {

  __shared__ __attribute__((aligned(16))) bf16 w1_lds[128 * 256];
  __shared__ __attribute__((aligned(16))) bf16 h_lds[64 * 128];

  const int tid = threadIdx.x;
  const int g  = blockIdx.x >> 6;
  const int bs = blockIdx.x & 63;
  const int l = g >> 1, ep = g & 1;
  const int* __restrict__ adj = (l == 0) ? a0 : (l == 1) ? a1 : (l == 2) ? a2 : a3;

  {
    const uint4* w1g = (const uint4*)(w1t + (size_t)g * 128 * 256);
    #pragma unroll
    for (int i = 0; i < 16; ++i) {
      int j = i * 256 + tid;
      int n = j >> 5, c = j & 31;
      *(uint4*)(&w1_lds[n * 256 + ((c ^ (n & 7)) << 3)]) = w1g[j];
    }
  }
  __syncthreads();

  const int w    = tid >> 6;
  const int lane = tid & 63;
  const int wr = w >> 1, wc = w & 1;
  const int l15 = lane & 15, q = lane >> 4;
  const bf16* __restrict__ w2g = w2t + (size_t)g * 128 * 128;

  for (int t = bs; t < 2500; t += 64) {
    const int ebase = t * 64;
    int2 pr0 = ((const int2*)adj)[ebase + 32 * wr + l15];
    int2 pr1 = ((const int2*)adj)[ebase + 32 * wr + 16 + l15];
    pr0.x = clampV(pr0.x); pr0.y = clampV(pr0.y);
    pr1.x = clampV(pr1.x); pr1.y = clampV(pr1.y);

    f32x4 acc[2][4] = {};
    #pragma unroll
    for (int kb = 0; kb < 8; ++kb) {
      const int k = kb * 32 + q * 8;
      const int klo = k & 127;
      const int n0 = (kb < 4) ? pr0.x : pr0.y;
      const int n1 = (kb < 4) ? pr1.x : pr1.y;
      bf16x8 a[2], b[4];
      a[0] = *(const bf16x8*)(embB + (size_t)n0 * 128 + klo);
      a[1] = *(const bf16x8*)(embB + (size_t)n1 * 128 + klo);
      const int csw = ((kb << 2) + q);
      #pragma unroll
      for (int nt = 0; nt < 4; ++nt) {
        int n = 64 * wc + 16 * nt + l15;
        b[nt] = *(const bf16x8*)(&w1_lds[n * 256 + ((csw ^ (l15 & 7)) << 3)]);
      }
      #pragma unroll
      for (int mt = 0; mt < 2; ++mt)
        #pragma unroll
        for (int nt = 0; nt < 4; ++nt)
          acc[mt][nt] = __builtin_amdgcn_mfma_f32_16x16x32_bf16(a[mt], b[nt], acc[mt][nt], 0, 0, 0);
    }

    __syncthreads();
    #pragma unroll
    for (int mt = 0; mt < 2; ++mt)
      #pragma unroll
      for (int nt = 0; nt < 4; ++nt)
        #pragma unroll
        for (int r = 0; r < 4; ++r) {
          float v = acc[mt][nt][r];
          v = v > 0.f ? v : 0.f;
          int row = 32 * wr + 16 * mt + 4 * q + r;
          int col = 64 * wc + 16 * nt + l15;
          int c = col >> 3;
          h_lds[row * 128 + (((c ^ (row & 7)) << 3) | (col & 7))] = (bf16)v;
        }
    __syncthreads();

    f32x4 acc2[2][4] = {};
    #pragma unroll
    for (int kb = 0; kb < 4; ++kb) {
      const int k = kb * 32 + q * 8;
      const int csw = (kb << 2) + q;
      bf16x8 a[2], b[4];
      #pragma unroll
      for (int mt = 0; mt < 2; ++mt) {
        int row = 32 * wr + 16 * mt + l15;
        a[mt] = *(const bf16x8*)(&h_lds[row * 128 + ((csw ^ (row & 7)) << 3)]);
      }
      #pragma unroll
      for (int nt = 0; nt < 4; ++nt) {
        int n = 64 * wc + 16 * nt + l15;
        b[nt] = *(const bf16x8*)(w2g + n * 128 + k);
      }
      #pragma unroll
      for (int mt = 0; mt < 2; ++mt)
        #pragma unroll
        for (int nt = 0; nt < 4; ++nt)
          acc2[mt][nt] = __builtin_amdgcn_mfma_f32_16x16x32_bf16(a[mt], b[nt], acc2[mt][nt], 0, 0, 0);
    }

    #pragma unroll
    for (int mt = 0; mt < 2; ++mt)
      #pragma unroll
      for (int r = 0; r < 4; ++r) {
        int row = 32 * wr + 16 * mt + 4 * q + r;
        int2 pr = ((const int2*)adj)[ebase + row];
        int node = clampV(ep ? pr.y : pr.x);
        float* basep = out + (size_t)node * 128 + 64 * wc + l15;
        #pragma unroll
        for (int nt = 0; nt < 4; ++nt)
          unsafeAtomicAdd(basep + 16 * nt, acc2[mt][nt][r]);
      }
  }
}

// ---------------- host launch ----------------------------------------------

extern "C" void kernel_launch(void* const* d_in, const int* in_sizes, int n_in,
                              void* d_out, int out_size, void* d_ws, size_t ws_size,
                              hipStream_t stream) {
  const float* emb = (const float*)d_in[0];
  const int* a0 = (const int*)d_in[1];
  const int* a1 = (const int*)d_in[2];
  const int* a2 = (const int*)d_in[3];
  const int* a3 = (const int*)d_in[4];
  const float* W1 = (const float*)d_in[5];
  const float* W2 = (const float*)d_in[6];
  float* out = (float*)d_out;

  char* ws = (char*)d_ws;
  // main-path layout (need 108.3 MB < known-good 116 MB floor):
  bf16* w1t  = (bf16*)(ws);                    //    524,288
  bf16* w2t  = (bf16*)(ws + 524288);           //    262,144
  int*  ids  = (int*) (ws + 786432);           //  5,120,000
  bf16* Hagg = (bf16*)(ws + 5906432);          // 102,400,000
  // CSR scratch overlays Hagg (dead before Hagg's memset):
  int* counts = (int*)(ws + 5906432);
  int* cursor = (int*)(ws + 5906432 + 1600000);
  int* offs   = (int*)(ws + 5906432 + 3200000);
  int* bsums  = (int*)(ws + 5906432 + 4800004);
  const size_t need_full = 5906432 + 102400000;   // 108,306,432
  // embB lives in the d_out region (12.8 MB <= 25.6 MB); gemm2 overwrites
  // the whole region at the end, and nothing reads embB after fused_k.
  bf16* embB = (bf16*)d_out;

  if (ws_size >= need_full) {
    prep_emb_k<<<6250, 256, 0, stream>>>(emb, embB);
    prep_w_k<<<1536, 256, 0, stream>>>(W1, W2, w1t, w2t);
    hipMemsetAsync(counts, 0, 3200000, stream);        // counts + cursor
    hist_k<<<dim3(625, 8), 256, 0, stream>>>(a0, a1, a2, a3, counts);
    scan_a_k<<<NBLK_SCAN, 256, 0, stream>>>(counts, offs, bsums);
    scan_b_k<<<1, 256, 0, stream>>>(bsums, offs);
    scan_c_k<<<1563, 256, 0, stream>>>(offs, bsums);
    scatter_ids_k<<<dim3(625, 8), 256, 0, stream>>>(a0, a1, a2, a3, offs, cursor, ids);
    hipMemsetAsync(Hagg, 0, 102400000, stream);
    fused_k<<<dim3(NBLK_FUSED, 8), 512, 0, stream>>>(embB, a0, a1, a2, a3, w1t, ids, Hagg);
    gemm2_k<<<782, 256, 0, stream>>>(Hagg, w2t, out);
  } else {
    // fallback: round-4 proven path, self-contained ws layout
    bf16* embB_f = (bf16*)(ws);                  // 12,800,000
    bf16* w1t_f  = (bf16*)(ws + 12800000);       //    524,288
    bf16* w2t_f  = (bf16*)(ws + 13324288);       //    262,144
    prep_emb_k<<<6250, 256, 0, stream>>>(emb, embB_f);
    prep_w_k<<<1536, 256, 0, stream>>>(W1, W2, w1t_f, w2t_f);
    hipMemsetAsync(d_out, 0, (size_t)V_NODES * 128 * sizeof(float), stream);
    edge_k<<<512, 256, 0, stream>>>(embB_f, a0, a1, a2, a3, w1t_f, w2t_f, out);
    relu_k<<<6250, 256, 0, stream>>>(out);
  }
}